// Round 6
// baseline (2938.908 us; speedup 1.0000x reference)
//
#include <hip/hip_runtime.h>
#include <math.h>

#define CH    512
#define FMPX  40
#define PW    42            // padded row width
#define PADN  1764          // 42*42
#define NP    1600          // 40*40
#define BATCH 8
#define NCLS  20
#define CONF_THR 0.001f
#define NMS_THR  0.6f

typedef _Float16 v8h __attribute__((ext_vector_type(8)));
typedef float    v4f __attribute__((ext_vector_type(4)));

// ws layout (in _Float16 units). 6 feature planes contiguous, then weights.
#define FPLANE  ((size_t)BATCH * PADN * CH)          // 7,225,344 halves
#define WSZ     ((size_t)9 * CH * CH)                // 2,359,296 halves

__device__ __forceinline__ int padidx(int p) { return p + 2 * (p / FMPX) + PW + 1; }

// async global->LDS, 16 B per lane
typedef __attribute__((address_space(1))) const void* gas_t;
typedef __attribute__((address_space(3))) void*       las_t;
__device__ __forceinline__ void gl2lds16(const void* g, void* l) {
    __builtin_amdgcn_global_load_lds((gas_t)g, (las_t)l, 16, 0, 0);
}

// ---------------------------------------------------------------------------
// Zero the padded borders of all 6 feature planes (ws re-poisoned each call).
// ---------------------------------------------------------------------------
__global__ __launch_bounds__(256)
void border_zero(uint4* __restrict__ ws) {
    int idx = blockIdx.x * 256 + threadIdx.x;           // grid 1968 blocks exact
    int u    = idx & 63;
    int cell = (idx >> 6) % 164;
    int b    = (idx / (64 * 164)) & 7;
    int pl   = idx / (64 * 164 * 8);
    int pi;
    if (cell < 42)      pi = cell;
    else if (cell < 84) pi = 41 * PW + (cell - 42);
    else { int r = cell - 84; pi = (1 + (r >> 1)) * PW + ((r & 1) ? 41 : 0); }
    size_t hoff = (size_t)pl * FPLANE + (size_t)b * (PADN * CH) + (size_t)pi * CH;
    ws[(hoff >> 3) + u] = make_uint4(0u, 0u, 0u, 0u);
}

// ---------------------------------------------------------------------------
// x [b][512][1600] fp32 -> padded pos-major fp16 hi/lo planes [b][1764][512].
// ---------------------------------------------------------------------------
__global__ __launch_bounds__(256)
void xprep_kernel(const float* __restrict__ x, _Float16* __restrict__ Xh,
                  _Float16* __restrict__ Xl) {
    __shared__ float T[64][65];
    const int t = threadIdx.x;
    const int p0  = blockIdx.x * 64;   // 25
    const int ci0 = blockIdx.y * 64;   // 8
    const int b   = blockIdx.z;        // 8
#pragma unroll
    for (int it = 0; it < 16; ++it) {
        int row = (t >> 6) + 4 * it;
        int col = t & 63;
        T[col][row] = x[((size_t)b * CH + ci0 + row) * NP + p0 + col];
    }
    __syncthreads();
#pragma unroll
    for (int it = 0; it < 16; ++it) {
        int posl = (t >> 6) + 4 * it;
        int ci   = t & 63;
        float v = T[posl][ci];
        _Float16 h = (_Float16)v;
        _Float16 l = (_Float16)((v - (float)h) * 2048.0f);
        size_t o = (size_t)b * (PADN * CH) + (size_t)padidx(p0 + posl) * CH + ci0 + ci;
        Xh[o] = h; Xl[o] = l;
    }
}

// ---------------------------------------------------------------------------
// w [co][ci][3][3] fp32 -> Wh/Wl [tap][co][ci] fp16.
// ---------------------------------------------------------------------------
__global__ __launch_bounds__(256)
void wtrans_kernel(const float* __restrict__ w, _Float16* __restrict__ Wh,
                   _Float16* __restrict__ Wl) {
    __shared__ float tile[32][289];
    const int t = threadIdx.x;
    const int co0 = blockIdx.x * 32;   // 16
    const int ci0 = blockIdx.y * 32;   // 16
#pragma unroll
    for (int g = 0; g < 36; ++g) {     // 32*288 = 9216
        int l = t + 256 * g;
        int co = l / 288, j = l - co * 288;
        tile[co][j] = w[(size_t)(co0 + co) * 4608 + ci0 * 9 + j];
    }
    __syncthreads();
#pragma unroll
    for (int tap = 0; tap < 9; ++tap) {
#pragma unroll
        for (int cg = 0; cg < 4; ++cg) {
            int co = cg * 8 + (t >> 5);
            int ci = t & 31;
            float v = tile[co][ci * 9 + tap];
            _Float16 h = (_Float16)(16.0f * v);
            _Float16 l = (_Float16)((v - (float)h * 0.0625f) * 32768.0f);
            size_t o = ((size_t)tap * CH + co0 + co) * CH + ci0 + ci;
            Wh[o] = h; Wl[o] = l;
        }
    }
}

// ---------------------------------------------------------------------------
// 3x3 conv via MFMA, split-fp16, m97-faithful K-loop:
// 800 blocks (tile 64 pos x 128 co), 4 waves (wave = 64 pos x 32 co),
// BK=64 per round (72 rounds), single 48 KB LDS buffer, __syncthreads
// barriers (compiler-managed waits), ~3 blocks/CU so co-resident blocks
// hide each other's barrier drains (m114/m97 mechanism).
// LDS map (halves): A_h[0,4096) A_l[4096,8192) B_h[8192,16384) B_l[16384,24576)
//   A_h slot (ks,i): ((ks*4+i)*64+l)*8   ks=k-substep, i=m-frag
//   B_h slot (ks,n): 8192+((ks*8+n)*64+l)*8   n=co-frag 0..7
// Per round per wave: 12 global_load_lds + 24 ds_read_b128 + 48 MFMA.
// ---------------------------------------------------------------------------
__global__ __launch_bounds__(256, 3)
void conv_mfma(const _Float16* __restrict__ Ih, const _Float16* __restrict__ Il,
               const _Float16* __restrict__ Wh, const _Float16* __restrict__ Wl,
               const float* __restrict__ bias,
               _Float16* __restrict__ Oh, _Float16* __restrict__ Ol) {
    __shared__ _Float16 sm[24576];   // 48 KB
    const int t = threadIdx.x;
    const int w = t >> 6, l = t & 63;
    const int quad = l >> 4, col = l & 15;
    const int bx = blockIdx.x;               // 0..199 = b*25 + ptile
    const int b  = bx / 25;
    const int p0 = (bx - b * 25) * 64;
    const int co0 = blockIdx.y * 128;        // gridDim.y = 4
    const size_t boff = (size_t)b * (PADN * CH);

    // ---- staging assignments ----
    // A: 8 slots (ks,i); wave w stages slots 2w, 2w+1 (per plane)
    size_t aSrc[2]; int aDst[2];
#pragma unroll
    for (int j = 0; j < 2; ++j) {
        int q = 2 * w + j, ks = q >> 2, i = q & 3;
        aSrc[j] = (size_t)padidx(p0 + i * 16 + col) * CH + ks * 32 + quad * 8;
        aDst[j] = q * 512 + l * 8;
    }
    // B: 16 slots (ks,n); wave w stages slots 4w..4w+3 (per plane)
    size_t bSrc[4]; int bDst[4];
#pragma unroll
    for (int j = 0; j < 4; ++j) {
        int q = 4 * w + j, ks = q >> 3, n = q & 7;
        bSrc[j] = (size_t)(co0 + n * 16 + col) * CH + ks * 32 + quad * 8;
        bDst[j] = 8192 + q * 512 + l * 8;
    }

    v4f acc1[4][2], acc2[4][2];
#pragma unroll
    for (int i = 0; i < 4; ++i)
#pragma unroll
        for (int j = 0; j < 2; ++j) {
            acc1[i][j] = (v4f){0.f, 0.f, 0.f, 0.f};
            acc2[i][j] = (v4f){0.f, 0.f, 0.f, 0.f};
        }

    for (int tap = 0; tap < 9; ++tap) {
        const int ty = tap / 3, tx = tap - 3 * ty;
        const int tsh = ((ty - 1) * PW + (tx - 1)) * CH;
        const _Float16* pAh = Ih + boff + tsh;
        const _Float16* pAl = Il + boff + tsh;
        const _Float16* pWh = Wh + (size_t)tap * (CH * CH);
        const _Float16* pWl = Wl + (size_t)tap * (CH * CH);
#pragma unroll 1
        for (int cc = 0; cc < CH; cc += 64) {
            __syncthreads();                 // prev round's LDS reads done
#pragma unroll
            for (int j = 0; j < 2; ++j) {
                gl2lds16(pAh + aSrc[j] + cc, sm + aDst[j]);
                gl2lds16(pAl + aSrc[j] + cc, sm + 4096 + aDst[j]);
            }
#pragma unroll
            for (int j = 0; j < 4; ++j) {
                gl2lds16(pWh + bSrc[j] + cc, sm + bDst[j]);
                gl2lds16(pWl + bSrc[j] + cc, sm + 8192 + bDst[j]);
            }
            __syncthreads();                 // staged data visible (vmcnt drained)

#pragma unroll
            for (int ks = 0; ks < 2; ++ks) {
                v8h ah[4], al[4];
#pragma unroll
                for (int i = 0; i < 4; ++i) {
                    ah[i] = *(const v8h*)(sm + (ks * 4 + i) * 512 + l * 8);
                    al[i] = *(const v8h*)(sm + 4096 + (ks * 4 + i) * 512 + l * 8);
                }
#pragma unroll
                for (int jj = 0; jj < 2; ++jj) {
                    v8h bh = *(const v8h*)(sm + 8192  + (ks * 8 + w * 2 + jj) * 512 + l * 8);
                    v8h bl = *(const v8h*)(sm + 16384 + (ks * 8 + w * 2 + jj) * 512 + l * 8);
#pragma unroll
                    for (int i = 0; i < 4; ++i)
                        acc1[i][jj] = __builtin_amdgcn_mfma_f32_16x16x32_f16(ah[i], bh, acc1[i][jj], 0, 0, 0);
#pragma unroll
                    for (int i = 0; i < 4; ++i)
                        acc2[i][jj] = __builtin_amdgcn_mfma_f32_16x16x32_f16(ah[i], bl, acc2[i][jj], 0, 0, 0);
#pragma unroll
                    for (int i = 0; i < 4; ++i)
                        acc2[i][jj] = __builtin_amdgcn_mfma_f32_16x16x32_f16(al[i], bh, acc2[i][jj], 0, 0, 0);
                }
            }
        }
    }

    // epilogue: combine, bias, leaky, split-store. wave covers co0+w*32 .. +31
#pragma unroll
    for (int i = 0; i < 4; ++i) {
#pragma unroll
        for (int jj = 0; jj < 2; ++jj) {
            int n = co0 + w * 32 + jj * 16 + col;
            float bv = bias[n];
#pragma unroll
            for (int r = 0; r < 4; ++r) {
                int p = p0 + i * 16 + quad * 4 + r;
                float v = acc1[i][jj][r] * 0.0625f + acc2[i][jj][r] * (1.0f / 32768.0f) + bv;
                v = v > 0.f ? v : 0.1f * v;
                _Float16 h = (_Float16)v;
                _Float16 lo = (_Float16)((v - (float)h) * 2048.0f);
                size_t o = boff + (size_t)padidx(p) * CH + n;
                Oh[o] = h; Ol[o] = lo;
            }
        }
    }
}

// ---------------------------------------------------------------------------
// Head: 1x1 convs + decode. One wave per (b,pos); lanes split ci (64x8=512).
// ---------------------------------------------------------------------------
__global__ __launch_bounds__(256)
void head_kernel(const _Float16* __restrict__ Rh, const _Float16* __restrict__ Rl,
                 const _Float16* __restrict__ Ch, const _Float16* __restrict__ Cl,
                 const float* __restrict__ objw, const float* __restrict__ objb,
                 const float* __restrict__ clsw, const float* __restrict__ clsb,
                 const float* __restrict__ regw, const float* __restrict__ regb,
                 float* __restrict__ out) {
    const int wid = (blockIdx.x * 256 + threadIdx.x) >> 6;  // 0..12799
    const int l = threadIdx.x & 63;
    const int b = wid / NP, p = wid - b * NP;
    const size_t base = (size_t)b * (PADN * CH) + (size_t)padidx(p) * CH + l * 8;

    v8h rh = *(const v8h*)(Rh + base), rl = *(const v8h*)(Rl + base);
    v8h ch = *(const v8h*)(Ch + base), cl = *(const v8h*)(Cl + base);
    float rv[8], cv[8];
#pragma unroll
    for (int k = 0; k < 8; ++k) {
        rv[k] = (float)rh[k] + (float)rl[k] * (1.0f / 2048.0f);
        cv[k] = (float)ch[k] + (float)cl[k] * (1.0f / 2048.0f);
    }
    float s[25];
#pragma unroll
    for (int o = 0; o < 25; ++o) s[o] = 0.f;
#pragma unroll
    for (int k = 0; k < 8; ++k) s[0] = fmaf(objw[l * 8 + k], rv[k], s[0]);
#pragma unroll
    for (int c = 0; c < NCLS; ++c)
#pragma unroll
        for (int k = 0; k < 8; ++k) s[1 + c] = fmaf(clsw[c * CH + l * 8 + k], cv[k], s[1 + c]);
#pragma unroll
    for (int q = 0; q < 4; ++q)
#pragma unroll
        for (int k = 0; k < 8; ++k) s[21 + q] = fmaf(regw[q * CH + l * 8 + k], rv[k], s[21 + q]);
#pragma unroll
    for (int o = 0; o < 25; ++o) {
#pragma unroll
        for (int off = 32; off > 0; off >>= 1) s[o] += __shfl_xor(s[o], off);
    }
    if (l == 0) {
        int gp = b * NP + p;
        float obj  = s[0] + objb[0];
        float sobj = 1.f / (1.f + expf(-obj));
        float lg[NCLS];
        float m = -1e30f; int am = 0;
#pragma unroll
        for (int c = 0; c < NCLS; ++c) {
            lg[c] = s[1 + c] + clsb[c];
            if (lg[c] > m) { m = lg[c]; am = c; }
        }
        float se = 0.f;
#pragma unroll
        for (int c = 0; c < NCLS; ++c) se += expf(lg[c] - m);
        float best = sobj / se;

        float r0 = s[21] + regb[0], r1 = s[22] + regb[1];
        float r2 = s[23] + regb[2], r3 = s[24] + regb[3];
        int gy = p / FMPX, gx = p - gy * FMPX;
        float cx = 1.f / (1.f + expf(-r0)) + (float)gx;
        float cy = 1.f / (1.f + expf(-r1)) + (float)gy;
        float hw = 0.5f * expf(r2);
        float hh = 0.5f * expf(r3);
        const float sc = 32.f / 1280.f;
        float x1 = fminf(fmaxf((cx - hw) * sc, 0.f), 1.f);
        float y1 = fminf(fmaxf((cy - hh) * sc, 0.f), 1.f);
        float x2 = fminf(fmaxf((cx + hw) * sc, 0.f), 1.f);
        float y2 = fminf(fmaxf((cy + hh) * sc, 0.f), 1.f);

        ((float4*)out)[gp] = make_float4(x1, y1, x2, y2);
        out[4 * BATCH * NP + gp] = best;
        out[5 * BATCH * NP + gp] = (float)am;
        out[6 * BATCH * NP + gp] = 0.f;
    }
}

// ---------------------------------------------------------------------------
// Sort-based greedy NMS (R5 version): 1024 thr, MLP kept-scan, shfl resolve.
// ---------------------------------------------------------------------------
__global__ __launch_bounds__(1024)
void nms_kernel(float* __restrict__ out) {
    const int c = blockIdx.x, b = blockIdx.y;
    const int t = threadIdx.x;
    const int w = t >> 6, l = t & 63;

    __shared__ unsigned long long skey[2048];
    __shared__ float4 CBox[NP];
    __shared__ float4 KBox[1664];       // kept, zero-padded to x64
    __shared__ unsigned long long wmask[16];
    __shared__ int Kcnt;

    for (int j = t; j < NP; j += 1024) {
        int gp = b * NP + j;
        float4 bx = ((const float4*)out)[gp];
        float best = out[4 * BATCH * NP + gp];
        int   ci   = (int)out[5 * BATCH * NP + gp];
        CBox[j] = bx;
        bool alive = (ci == c) && (best >= CONF_THR);
        unsigned long long key = alive
            ? ~(((unsigned long long)__float_as_uint(best) << 32)
                | (unsigned long long)(0xFFFFFFFFu - (unsigned)j))
            : ~0ull;
        skey[j] = key;
    }
    for (int j = NP + t; j < 2048; j += 1024) skey[j] = ~0ull;
    for (int j = t; j < 1664; j += 1024) KBox[j] = make_float4(0.f, 0.f, 0.f, 0.f);
    if (t == 0) Kcnt = 0;

    for (unsigned k = 2; k <= 2048; k <<= 1) {
        for (unsigned j = k >> 1; j > 0; j >>= 1) {
            __syncthreads();
            for (unsigned i = t; i < 2048; i += 1024) {
                unsigned p = i ^ j;
                if (p > i) {
                    bool up = ((i & k) == 0);
                    unsigned long long a = skey[i], bq = skey[p];
                    if ((a > bq) == up) { skey[i] = bq; skey[p] = a; }
                }
            }
        }
    }
    __syncthreads();

    float* keepout = out + 6 * BATCH * NP + b * NP;
    for (int base = 0; base < NP; base += 64) {
        unsigned long long ik = skey[base + l];
        bool valid = (ik != ~0ull);
        unsigned long long vm = __ballot(valid);
        if (vm == 0) break;

        unsigned idx = 0;
        float4 bx = make_float4(0.f, 0.f, 0.f, 0.f);
        float ar = 0.f;
        if (valid) {
            unsigned long long K = ~ik;
            idx = 0xFFFFFFFFu - (unsigned)(K & 0xFFFFFFFFull);
            bx  = CBox[idx];
            ar  = (bx.z - bx.x) * (bx.w - bx.y);
        }
        int prevK = Kcnt;
        int prevKpad = (prevK + 63) & ~63;

        bool sup = false;
        for (int kk = w * 4; kk < prevKpad; kk += 64) {
            float4 kb0 = KBox[kk],     kb1 = KBox[kk + 1];
            float4 kb2 = KBox[kk + 2], kb3 = KBox[kk + 3];
#pragma unroll
            for (int q = 0; q < 4; ++q) {
                float4 kb = q == 0 ? kb0 : q == 1 ? kb1 : q == 2 ? kb2 : kb3;
                float kar = (kb.z - kb.x) * (kb.w - kb.y);
                float xx1 = fmaxf(kb.x, bx.x);
                float yy1 = fmaxf(kb.y, bx.y);
                float xx2 = fminf(kb.z, bx.z);
                float yy2 = fminf(kb.w, bx.w);
                float ww = fmaxf(1e-28f, xx2 - xx1);
                float hh = fmaxf(1e-28f, yy2 - yy1);
                float inter = ww * hh;
                float iou = inter / (kar + ar - inter + 1e-14f);
                sup |= (iou > NMS_THR);
            }
        }
        wmask[w] = __ballot(valid && !sup);
        __syncthreads();

        if (w == 0) {
            unsigned long long alive = wmask[0];
#pragma unroll
            for (int q = 1; q < 16; ++q) alive &= wmask[q];
            unsigned long long smask = 0;
            for (int s = 0; s < 63; ++s) {
                float ox1 = __shfl(bx.x, s), oy1 = __shfl(bx.y, s);
                float ox2 = __shfl(bx.z, s), oy2 = __shfl(bx.w, s);
                float oar = (ox2 - ox1) * (oy2 - oy1);
                float xx1 = fmaxf(ox1, bx.x);
                float yy1 = fmaxf(oy1, bx.y);
                float xx2 = fminf(ox2, bx.z);
                float yy2 = fminf(oy2, bx.w);
                float ww = fmaxf(1e-28f, xx2 - xx1);
                float hh = fmaxf(1e-28f, yy2 - yy1);
                float inter = ww * hh;
                float iou = inter / (oar + ar - inter + 1e-14f);
                if (s < l && iou > NMS_THR) smask |= (1ull << s);
            }
            unsigned long long kept = 0;
            while (alive) {
                int s = __builtin_ctzll(alive);
                kept |= (1ull << s);
                alive &= ~(1ull << s);
                unsigned long long dead = __ballot((smask >> s) & 1ull);
                alive &= ~dead;
            }
            if ((kept >> l) & 1ull) {
                int pos = prevK + __builtin_popcountll(kept & ((1ull << l) - 1ull));
                KBox[pos] = bx;
                keepout[idx] = 1.0f;
            }
            if (l == 0) Kcnt = prevK + __builtin_popcountll(kept);
        }
        __syncthreads();
    }
}

// ---------------------------------------------------------------------------
extern "C" void kernel_launch(void* const* d_in, const int* in_sizes, int n_in,
                              void* d_out, int out_size, void* d_ws, size_t ws_size,
                              hipStream_t stream) {
    const float* x      = (const float*)d_in[0];
    const float* cls_w  = (const float*)d_in[1];
    const float* cls_b  = (const float*)d_in[2];
    const float* reg_w  = (const float*)d_in[3];
    const float* reg_b  = (const float*)d_in[4];
    const float* obj_w  = (const float*)d_in[5];
    const float* obj_b  = (const float*)d_in[6];
    const float* clsp_w = (const float*)d_in[7];
    const float* clsp_b = (const float*)d_in[8];
    const float* regp_w = (const float*)d_in[9];
    const float* regp_b = (const float*)d_in[10];
    float* out = (float*)d_out;

    _Float16* ws = (_Float16*)d_ws;
    _Float16* Xh = ws;
    _Float16* Xl = ws + FPLANE;
    _Float16* Ah = ws + 2 * FPLANE;
    _Float16* Al = ws + 3 * FPLANE;
    _Float16* Bh = ws + 4 * FPLANE;
    _Float16* Bl = ws + 5 * FPLANE;
    _Float16* Wh = ws + 6 * FPLANE;
    _Float16* Wl = Wh + WSZ;
    const size_t LW = (size_t)CH * CH * 9;

    border_zero<<<dim3(1968), 256, 0, stream>>>((uint4*)d_ws);
    xprep_kernel<<<dim3(25, 8, 8), 256, 0, stream>>>(x, Xh, Xl);

    dim3 wgrid(16, 16), cgrid(200, 4), blk(256);

    // cls chain: xp -> A -> B (cf = B)
    wtrans_kernel<<<wgrid, blk, 0, stream>>>(cls_w, Wh, Wl);
    conv_mfma<<<cgrid, blk, 0, stream>>>(Xh, Xl, Wh, Wl, cls_b,          Ah, Al);
    wtrans_kernel<<<wgrid, blk, 0, stream>>>(cls_w + LW, Wh, Wl);
    conv_mfma<<<cgrid, blk, 0, stream>>>(Ah, Al, Wh, Wl, cls_b + CH,     Bh, Bl);
    // reg chain: xp -> A -> xp -> A -> xp (rf = xp)
    wtrans_kernel<<<wgrid, blk, 0, stream>>>(reg_w, Wh, Wl);
    conv_mfma<<<cgrid, blk, 0, stream>>>(Xh, Xl, Wh, Wl, reg_b,          Ah, Al);
    wtrans_kernel<<<wgrid, blk, 0, stream>>>(reg_w + LW, Wh, Wl);
    conv_mfma<<<cgrid, blk, 0, stream>>>(Ah, Al, Wh, Wl, reg_b + CH,     Xh, Xl);
    wtrans_kernel<<<wgrid, blk, 0, stream>>>(reg_w + 2 * LW, Wh, Wl);
    conv_mfma<<<cgrid, blk, 0, stream>>>(Xh, Xl, Wh, Wl, reg_b + 2 * CH, Ah, Al);
    wtrans_kernel<<<wgrid, blk, 0, stream>>>(reg_w + 3 * LW, Wh, Wl);
    conv_mfma<<<cgrid, blk, 0, stream>>>(Ah, Al, Wh, Wl, reg_b + 3 * CH, Xh, Xl);

    head_kernel<<<dim3(3200), 256, 0, stream>>>(Xh, Xl, Bh, Bl, obj_w, obj_b,
                                                clsp_w, clsp_b, regp_w, regp_b, out);
    nms_kernel<<<dim3(NCLS, BATCH), 1024, 0, stream>>>(out);
}

// Round 7
// 2410.560 us; speedup vs baseline: 1.2192x; 1.2192x over previous
//
#include <hip/hip_runtime.h>
#include <math.h>

#define CH    512
#define FMPX  40
#define PW    42            // padded row width
#define PADN  1764          // 42*42
#define NP    1600          // 40*40
#define BATCH 8
#define NCLS  20
#define CONF_THR 0.001f
#define NMS_THR  0.6f

typedef _Float16 v8h __attribute__((ext_vector_type(8)));
typedef float    v4f __attribute__((ext_vector_type(4)));

// ws layout (in _Float16 units): 8 feature planes (4 hi/lo pairs: X,A,B,C),
// then 2 transposed-weight sets (hi/lo each).  Total 134.5 MB.
#define FPLANE  ((size_t)BATCH * PADN * CH)          // 7,225,344 halves
#define WSZ     ((size_t)9 * CH * CH)                // 2,359,296 halves

__device__ __forceinline__ int padidx(int p) { return p + 2 * (p / FMPX) + PW + 1; }

// async global->LDS, 16 B per lane
typedef __attribute__((address_space(1))) const void* gas_t;
typedef __attribute__((address_space(3))) void*       las_t;
__device__ __forceinline__ void gl2lds16(const void* g, void* l) {
    __builtin_amdgcn_global_load_lds((gas_t)g, (las_t)l, 16, 0, 0);
}

// ---------------------------------------------------------------------------
// Zero the padded borders of all 8 feature planes (ws re-poisoned each call).
// 8 planes * 8 b * 164 border cells * 64 uint4 -> 2624 blocks exact.
// ---------------------------------------------------------------------------
__global__ __launch_bounds__(256)
void border_zero(uint4* __restrict__ ws) {
    int idx = blockIdx.x * 256 + threadIdx.x;
    int u    = idx & 63;
    int cell = (idx >> 6) % 164;
    int b    = (idx / (64 * 164)) & 7;
    int pl   = idx / (64 * 164 * 8);          // 0..7
    int pi;
    if (cell < 42)      pi = cell;
    else if (cell < 84) pi = 41 * PW + (cell - 42);
    else { int r = cell - 84; pi = (1 + (r >> 1)) * PW + ((r & 1) ? 41 : 0); }
    size_t hoff = (size_t)pl * FPLANE + (size_t)b * (PADN * CH) + (size_t)pi * CH;
    ws[(hoff >> 3) + u] = make_uint4(0u, 0u, 0u, 0u);
}

// ---------------------------------------------------------------------------
// x [b][512][1600] fp32 -> padded pos-major fp16 hi/lo planes [b][1764][512].
// ---------------------------------------------------------------------------
__global__ __launch_bounds__(256)
void xprep_kernel(const float* __restrict__ x, _Float16* __restrict__ Xh,
                  _Float16* __restrict__ Xl) {
    __shared__ float T[64][65];
    const int t = threadIdx.x;
    const int p0  = blockIdx.x * 64;   // 25
    const int ci0 = blockIdx.y * 64;   // 8
    const int b   = blockIdx.z;        // 8
#pragma unroll
    for (int it = 0; it < 16; ++it) {
        int row = (t >> 6) + 4 * it;
        int col = t & 63;
        T[col][row] = x[((size_t)b * CH + ci0 + row) * NP + p0 + col];
    }
    __syncthreads();
#pragma unroll
    for (int it = 0; it < 16; ++it) {
        int posl = (t >> 6) + 4 * it;
        int ci   = t & 63;
        float v = T[posl][ci];
        _Float16 h = (_Float16)v;
        _Float16 l = (_Float16)((v - (float)h) * 2048.0f);
        size_t o = (size_t)b * (PADN * CH) + (size_t)padidx(p0 + posl) * CH + ci0 + ci;
        Xh[o] = h; Xl[o] = l;
    }
}

// ---------------------------------------------------------------------------
// w [co][ci][3][3] fp32 -> Wh/Wl [tap][co][ci] fp16.
// ---------------------------------------------------------------------------
__global__ __launch_bounds__(256)
void wtrans_kernel(const float* __restrict__ w, _Float16* __restrict__ Wh,
                   _Float16* __restrict__ Wl) {
    __shared__ float tile[32][289];
    const int t = threadIdx.x;
    const int co0 = blockIdx.x * 32;   // 16
    const int ci0 = blockIdx.y * 32;   // 16
#pragma unroll
    for (int g = 0; g < 36; ++g) {     // 32*288 = 9216
        int l = t + 256 * g;
        int co = l / 288, j = l - co * 288;
        tile[co][j] = w[(size_t)(co0 + co) * 4608 + ci0 * 9 + j];
    }
    __syncthreads();
#pragma unroll
    for (int tap = 0; tap < 9; ++tap) {
#pragma unroll
        for (int cg = 0; cg < 4; ++cg) {
            int co = cg * 8 + (t >> 5);
            int ci = t & 31;
            float v = tile[co][ci * 9 + tap];
            _Float16 h = (_Float16)(16.0f * v);
            _Float16 l = (_Float16)((v - (float)h * 0.0625f) * 32768.0f);
            size_t o = ((size_t)tap * CH + co0 + co) * CH + ci0 + ci;
            Wh[o] = h; Wl[o] = l;
        }
    }
}

// ---------------------------------------------------------------------------
// Dual 3x3 conv via MFMA, split-fp16 — R4-proven internals (64pos x 256co,
// BK=32, 40 KB single LDS buffer, __syncthreads), fused over TWO independent
// convs so the grid reaches ~3 blocks/CU (m97/m114 overlap regime).
// Block decode (1D grid, nconv*400 blocks):
//   b = bid & 7 (XCD swizzle: batch -> XCD for L2 input locality)
//   q = bid >> 3;  cid = q / 50;  r = q % 50;  cos = r & 1;  pt = r >> 1
// LDS (halves): A_h[0,2048) A_l[2048,4096) B_h[4096,12288) B_l[12288,20480)
// ---------------------------------------------------------------------------
__global__ __launch_bounds__(256, 2)
void conv_dual(const _Float16* __restrict__ I0h, const _Float16* __restrict__ I0l,
               const _Float16* __restrict__ W0h, const _Float16* __restrict__ W0l,
               const float* __restrict__ bias0,
               _Float16* __restrict__ O0h, _Float16* __restrict__ O0l,
               const _Float16* __restrict__ I1h, const _Float16* __restrict__ I1l,
               const _Float16* __restrict__ W1h, const _Float16* __restrict__ W1l,
               const float* __restrict__ bias1,
               _Float16* __restrict__ O1h, _Float16* __restrict__ O1l) {
    __shared__ _Float16 sm[20480];   // 40 KB
    const int t = threadIdx.x;
    const int w = t >> 6, l = t & 63;
    const int quad = l >> 4, col = l & 15;

    const int bid = blockIdx.x;
    const int b   = bid & 7;
    const int q   = bid >> 3;
    const int cid = q / 50;
    const int r   = q - 50 * cid;
    const int co0 = (r & 1) * 256;
    const int p0  = (r >> 1) * 64;

    const _Float16* Ih = cid ? I1h : I0h;
    const _Float16* Il = cid ? I1l : I0l;
    const _Float16* Wh = cid ? W1h : W0h;
    const _Float16* Wl = cid ? W1l : W0l;
    const float*  bias = cid ? bias1 : bias0;
    _Float16* Oh = cid ? O1h : O0h;
    _Float16* Ol = cid ? O1l : O0l;

    const size_t boff = (size_t)b * (PADN * CH);

    // lane-dependent global source offsets (halves)
    const size_t aG = boff + (size_t)padidx(p0 + w * 16 + col) * CH + quad * 8;
    size_t bG[4];
#pragma unroll
    for (int j = 0; j < 4; ++j)
        bG[j] = (size_t)(co0 + w * 64 + j * 16 + col) * CH + quad * 8;

    // LDS staging dest offsets (halves)
    const int aD = (w * 64 + l) * 8;
    int bD[4];
#pragma unroll
    for (int j = 0; j < 4; ++j) bD[j] = 4096 + ((w * 4 + j) * 64 + l) * 8;

    v4f acc1[4][4], acc2[4][4];
#pragma unroll
    for (int i = 0; i < 4; ++i)
#pragma unroll
        for (int j = 0; j < 4; ++j) {
            acc1[i][j] = (v4f){0.f, 0.f, 0.f, 0.f};
            acc2[i][j] = (v4f){0.f, 0.f, 0.f, 0.f};
        }

    for (int tap = 0; tap < 9; ++tap) {
        const int dy = tap / 3 - 1, dx = tap - (tap / 3) * 3 - 1;
        const int tsh = (dy * PW + dx) * CH;
        const _Float16* gAh = Ih + aG + tsh;
        const _Float16* gAl = Il + aG + tsh;
        const _Float16* gWh = Wh + (size_t)tap * (CH * CH);
        const _Float16* gWl = Wl + (size_t)tap * (CH * CH);
#pragma unroll 1
        for (int kc = 0; kc < 16; ++kc) {
            const int c0 = kc * 32;
            __syncthreads();                 // prev chunk's LDS reads done
            gl2lds16(gAh + c0, sm + aD);
            gl2lds16(gAl + c0, sm + 2048 + aD);
#pragma unroll
            for (int j = 0; j < 4; ++j) {
                gl2lds16(gWh + bG[j] + c0, sm + bD[j]);
                gl2lds16(gWl + bG[j] + c0, sm + 8192 + bD[j]);
            }
            __syncthreads();                 // staged data visible

            v8h ah[4], al[4];
#pragma unroll
            for (int i = 0; i < 4; ++i) {
                ah[i] = *(const v8h*)(sm + (i * 64 + l) * 8);
                al[i] = *(const v8h*)(sm + 2048 + (i * 64 + l) * 8);
            }
#pragma unroll
            for (int j = 0; j < 4; ++j) {
                v8h bh = *(const v8h*)(sm + 4096  + ((w * 4 + j) * 64 + l) * 8);
                v8h bl = *(const v8h*)(sm + 12288 + ((w * 4 + j) * 64 + l) * 8);
#pragma unroll
                for (int i = 0; i < 4; ++i)
                    acc1[i][j] = __builtin_amdgcn_mfma_f32_16x16x32_f16(ah[i], bh, acc1[i][j], 0, 0, 0);
#pragma unroll
                for (int i = 0; i < 4; ++i)
                    acc2[i][j] = __builtin_amdgcn_mfma_f32_16x16x32_f16(ah[i], bl, acc2[i][j], 0, 0, 0);
#pragma unroll
                for (int i = 0; i < 4; ++i)
                    acc2[i][j] = __builtin_amdgcn_mfma_f32_16x16x32_f16(al[i], bh, acc2[i][j], 0, 0, 0);
            }
        }
    }

    // epilogue: combine, bias, leaky, split-store. wave covers co0+w*64 .. +63
#pragma unroll
    for (int i = 0; i < 4; ++i) {
#pragma unroll
        for (int j = 0; j < 4; ++j) {
            int n = co0 + w * 64 + j * 16 + col;
            float bv = bias[n];
#pragma unroll
            for (int rr = 0; rr < 4; ++rr) {
                int p = p0 + i * 16 + quad * 4 + rr;
                float v = acc1[i][j][rr] * 0.0625f + acc2[i][j][rr] * (1.0f / 32768.0f) + bv;
                v = v > 0.f ? v : 0.1f * v;
                _Float16 h = (_Float16)v;
                _Float16 lo = (_Float16)((v - (float)h) * 2048.0f);
                size_t o = boff + (size_t)padidx(p) * CH + n;
                Oh[o] = h; Ol[o] = lo;
            }
        }
    }
}

// ---------------------------------------------------------------------------
// Head: 1x1 convs + decode. One wave per (b,pos); lanes split ci (64x8=512).
// ---------------------------------------------------------------------------
__global__ __launch_bounds__(256)
void head_kernel(const _Float16* __restrict__ Rh, const _Float16* __restrict__ Rl,
                 const _Float16* __restrict__ Ch, const _Float16* __restrict__ Cl,
                 const float* __restrict__ objw, const float* __restrict__ objb,
                 const float* __restrict__ clsw, const float* __restrict__ clsb,
                 const float* __restrict__ regw, const float* __restrict__ regb,
                 float* __restrict__ out) {
    const int wid = (blockIdx.x * 256 + threadIdx.x) >> 6;  // 0..12799
    const int l = threadIdx.x & 63;
    const int b = wid / NP, p = wid - b * NP;
    const size_t base = (size_t)b * (PADN * CH) + (size_t)padidx(p) * CH + l * 8;

    v8h rh = *(const v8h*)(Rh + base), rl = *(const v8h*)(Rl + base);
    v8h ch = *(const v8h*)(Ch + base), cl = *(const v8h*)(Cl + base);
    float rv[8], cv[8];
#pragma unroll
    for (int k = 0; k < 8; ++k) {
        rv[k] = (float)rh[k] + (float)rl[k] * (1.0f / 2048.0f);
        cv[k] = (float)ch[k] + (float)cl[k] * (1.0f / 2048.0f);
    }
    float s[25];
#pragma unroll
    for (int o = 0; o < 25; ++o) s[o] = 0.f;
#pragma unroll
    for (int k = 0; k < 8; ++k) s[0] = fmaf(objw[l * 8 + k], rv[k], s[0]);
#pragma unroll
    for (int c = 0; c < NCLS; ++c)
#pragma unroll
        for (int k = 0; k < 8; ++k) s[1 + c] = fmaf(clsw[c * CH + l * 8 + k], cv[k], s[1 + c]);
#pragma unroll
    for (int q = 0; q < 4; ++q)
#pragma unroll
        for (int k = 0; k < 8; ++k) s[21 + q] = fmaf(regw[q * CH + l * 8 + k], rv[k], s[21 + q]);
#pragma unroll
    for (int o = 0; o < 25; ++o) {
#pragma unroll
        for (int off = 32; off > 0; off >>= 1) s[o] += __shfl_xor(s[o], off);
    }
    if (l == 0) {
        int gp = b * NP + p;
        float obj  = s[0] + objb[0];
        float sobj = 1.f / (1.f + expf(-obj));
        float lg[NCLS];
        float m = -1e30f; int am = 0;
#pragma unroll
        for (int c = 0; c < NCLS; ++c) {
            lg[c] = s[1 + c] + clsb[c];
            if (lg[c] > m) { m = lg[c]; am = c; }
        }
        float se = 0.f;
#pragma unroll
        for (int c = 0; c < NCLS; ++c) se += expf(lg[c] - m);
        float best = sobj / se;

        float r0 = s[21] + regb[0], r1 = s[22] + regb[1];
        float r2 = s[23] + regb[2], r3 = s[24] + regb[3];
        int gy = p / FMPX, gx = p - gy * FMPX;
        float cx = 1.f / (1.f + expf(-r0)) + (float)gx;
        float cy = 1.f / (1.f + expf(-r1)) + (float)gy;
        float hw = 0.5f * expf(r2);
        float hh = 0.5f * expf(r3);
        const float sc = 32.f / 1280.f;
        float x1 = fminf(fmaxf((cx - hw) * sc, 0.f), 1.f);
        float y1 = fminf(fmaxf((cy - hh) * sc, 0.f), 1.f);
        float x2 = fminf(fmaxf((cx + hw) * sc, 0.f), 1.f);
        float y2 = fminf(fmaxf((cy + hh) * sc, 0.f), 1.f);

        ((float4*)out)[gp] = make_float4(x1, y1, x2, y2);
        out[4 * BATCH * NP + gp] = best;
        out[5 * BATCH * NP + gp] = (float)am;
        out[6 * BATCH * NP + gp] = 0.f;
    }
}

// ---------------------------------------------------------------------------
// Sort-based greedy NMS: 1024 thr, MLP kept-scan, shfl resolve. (unchanged)
// ---------------------------------------------------------------------------
__global__ __launch_bounds__(1024)
void nms_kernel(float* __restrict__ out) {
    const int c = blockIdx.x, b = blockIdx.y;
    const int t = threadIdx.x;
    const int w = t >> 6, l = t & 63;

    __shared__ unsigned long long skey[2048];
    __shared__ float4 CBox[NP];
    __shared__ float4 KBox[1664];
    __shared__ unsigned long long wmask[16];
    __shared__ int Kcnt;

    for (int j = t; j < NP; j += 1024) {
        int gp = b * NP + j;
        float4 bx = ((const float4*)out)[gp];
        float best = out[4 * BATCH * NP + gp];
        int   ci   = (int)out[5 * BATCH * NP + gp];
        CBox[j] = bx;
        bool alive = (ci == c) && (best >= CONF_THR);
        unsigned long long key = alive
            ? ~(((unsigned long long)__float_as_uint(best) << 32)
                | (unsigned long long)(0xFFFFFFFFu - (unsigned)j))
            : ~0ull;
        skey[j] = key;
    }
    for (int j = NP + t; j < 2048; j += 1024) skey[j] = ~0ull;
    for (int j = t; j < 1664; j += 1024) KBox[j] = make_float4(0.f, 0.f, 0.f, 0.f);
    if (t == 0) Kcnt = 0;

    for (unsigned k = 2; k <= 2048; k <<= 1) {
        for (unsigned j = k >> 1; j > 0; j >>= 1) {
            __syncthreads();
            for (unsigned i = t; i < 2048; i += 1024) {
                unsigned p = i ^ j;
                if (p > i) {
                    bool up = ((i & k) == 0);
                    unsigned long long a = skey[i], bq = skey[p];
                    if ((a > bq) == up) { skey[i] = bq; skey[p] = a; }
                }
            }
        }
    }
    __syncthreads();

    float* keepout = out + 6 * BATCH * NP + b * NP;
    for (int base = 0; base < NP; base += 64) {
        unsigned long long ik = skey[base + l];
        bool valid = (ik != ~0ull);
        unsigned long long vm = __ballot(valid);
        if (vm == 0) break;

        unsigned idx = 0;
        float4 bx = make_float4(0.f, 0.f, 0.f, 0.f);
        float ar = 0.f;
        if (valid) {
            unsigned long long K = ~ik;
            idx = 0xFFFFFFFFu - (unsigned)(K & 0xFFFFFFFFull);
            bx  = CBox[idx];
            ar  = (bx.z - bx.x) * (bx.w - bx.y);
        }
        int prevK = Kcnt;
        int prevKpad = (prevK + 63) & ~63;

        bool sup = false;
        for (int kk = w * 4; kk < prevKpad; kk += 64) {
            float4 kb0 = KBox[kk],     kb1 = KBox[kk + 1];
            float4 kb2 = KBox[kk + 2], kb3 = KBox[kk + 3];
#pragma unroll
            for (int q = 0; q < 4; ++q) {
                float4 kb = q == 0 ? kb0 : q == 1 ? kb1 : q == 2 ? kb2 : kb3;
                float kar = (kb.z - kb.x) * (kb.w - kb.y);
                float xx1 = fmaxf(kb.x, bx.x);
                float yy1 = fmaxf(kb.y, bx.y);
                float xx2 = fminf(kb.z, bx.z);
                float yy2 = fminf(kb.w, bx.w);
                float ww = fmaxf(1e-28f, xx2 - xx1);
                float hh = fmaxf(1e-28f, yy2 - yy1);
                float inter = ww * hh;
                float iou = inter / (kar + ar - inter + 1e-14f);
                sup |= (iou > NMS_THR);
            }
        }
        wmask[w] = __ballot(valid && !sup);
        __syncthreads();

        if (w == 0) {
            unsigned long long alive = wmask[0];
#pragma unroll
            for (int q = 1; q < 16; ++q) alive &= wmask[q];
            unsigned long long smask = 0;
            for (int s = 0; s < 63; ++s) {
                float ox1 = __shfl(bx.x, s), oy1 = __shfl(bx.y, s);
                float ox2 = __shfl(bx.z, s), oy2 = __shfl(bx.w, s);
                float oar = (ox2 - ox1) * (oy2 - oy1);
                float xx1 = fmaxf(ox1, bx.x);
                float yy1 = fmaxf(oy1, bx.y);
                float xx2 = fminf(ox2, bx.z);
                float yy2 = fminf(oy2, bx.w);
                float ww = fmaxf(1e-28f, xx2 - xx1);
                float hh = fmaxf(1e-28f, yy2 - yy1);
                float inter = ww * hh;
                float iou = inter / (oar + ar - inter + 1e-14f);
                if (s < l && iou > NMS_THR) smask |= (1ull << s);
            }
            unsigned long long kept = 0;
            while (alive) {
                int s = __builtin_ctzll(alive);
                kept |= (1ull << s);
                alive &= ~(1ull << s);
                unsigned long long dead = __ballot((smask >> s) & 1ull);
                alive &= ~dead;
            }
            if ((kept >> l) & 1ull) {
                int pos = prevK + __builtin_popcountll(kept & ((1ull << l) - 1ull));
                KBox[pos] = bx;
                keepout[idx] = 1.0f;
            }
            if (l == 0) Kcnt = prevK + __builtin_popcountll(kept);
        }
        __syncthreads();
    }
}

// ---------------------------------------------------------------------------
extern "C" void kernel_launch(void* const* d_in, const int* in_sizes, int n_in,
                              void* d_out, int out_size, void* d_ws, size_t ws_size,
                              hipStream_t stream) {
    const float* x      = (const float*)d_in[0];
    const float* cls_w  = (const float*)d_in[1];
    const float* cls_b  = (const float*)d_in[2];
    const float* reg_w  = (const float*)d_in[3];
    const float* reg_b  = (const float*)d_in[4];
    const float* obj_w  = (const float*)d_in[5];
    const float* obj_b  = (const float*)d_in[6];
    const float* clsp_w = (const float*)d_in[7];
    const float* clsp_b = (const float*)d_in[8];
    const float* regp_w = (const float*)d_in[9];
    const float* regp_b = (const float*)d_in[10];
    float* out = (float*)d_out;

    _Float16* ws = (_Float16*)d_ws;
    _Float16* Xh = ws;                     // pair 0
    _Float16* Xl = ws + FPLANE;
    _Float16* Ah = ws + 2 * FPLANE;        // pair 1
    _Float16* Al = ws + 3 * FPLANE;
    _Float16* Bh = ws + 4 * FPLANE;        // pair 2
    _Float16* Bl = ws + 5 * FPLANE;
    _Float16* Ch = ws + 6 * FPLANE;        // pair 3
    _Float16* Cl = ws + 7 * FPLANE;
    _Float16* W0h = ws + 8 * FPLANE;       // weight set 0
    _Float16* W0l = W0h + WSZ;
    _Float16* W1h = W0l + WSZ;             // weight set 1
    _Float16* W1l = W1h + WSZ;
    const size_t LW = (size_t)CH * CH * 9;

    border_zero<<<dim3(2624), 256, 0, stream>>>((uint4*)d_ws);
    xprep_kernel<<<dim3(25, 8, 8), 256, 0, stream>>>(x, Xh, Xl);

    dim3 wgrid(16, 16), blk(256);

    // D1: cls1 (X->A) || reg1 (X->C)
    wtrans_kernel<<<wgrid, blk, 0, stream>>>(cls_w, W0h, W0l);
    wtrans_kernel<<<wgrid, blk, 0, stream>>>(reg_w, W1h, W1l);
    conv_dual<<<dim3(800), blk, 0, stream>>>(Xh, Xl, W0h, W0l, cls_b,      Ah, Al,
                                             Xh, Xl, W1h, W1l, reg_b,      Ch, Cl);
    // D2: cls2 (A->B) || reg2 (C->X)
    wtrans_kernel<<<wgrid, blk, 0, stream>>>(cls_w + LW, W0h, W0l);
    wtrans_kernel<<<wgrid, blk, 0, stream>>>(reg_w + LW, W1h, W1l);
    conv_dual<<<dim3(800), blk, 0, stream>>>(Ah, Al, W0h, W0l, cls_b + CH, Bh, Bl,
                                             Ch, Cl, W1h, W1l, reg_b + CH, Xh, Xl);
    // D3: reg3 (X->C)
    wtrans_kernel<<<wgrid, blk, 0, stream>>>(reg_w + 2 * LW, W0h, W0l);
    conv_dual<<<dim3(400), blk, 0, stream>>>(Xh, Xl, W0h, W0l, reg_b + 2 * CH, Ch, Cl,
                                             Xh, Xl, W0h, W0l, reg_b + 2 * CH, Ch, Cl);
    // D4: reg4 (C->X)
    wtrans_kernel<<<wgrid, blk, 0, stream>>>(reg_w + 3 * LW, W0h, W0l);
    conv_dual<<<dim3(400), blk, 0, stream>>>(Ch, Cl, W0h, W0l, reg_b + 3 * CH, Xh, Xl,
                                             Ch, Cl, W0h, W0l, reg_b + 3 * CH, Xh, Xl);

    head_kernel<<<dim3(3200), 256, 0, stream>>>(Xh, Xl, Bh, Bl, obj_w, obj_b,
                                                clsp_w, clsp_b, regp_w, regp_b, out);
    nms_kernel<<<dim3(NCLS, BATCH), 1024, 0, stream>>>(out);
}